// Round 1
// baseline (31.879 us; speedup 1.0000x reference)
//
#include <hip/hip_runtime.h>

// AdLIF neuron scan: x [B=32, T=512, D=1024] f32 -> spikes [B, T, D] f32.
// One thread per (b, d) channel; sequential over T with 2x16-deep register
// prefetch ping-pong to keep ~32 loads in flight per wave (512 waves total).
//
// FP order matches the JAX reference exactly (mul then add, round-to-nearest,
// NO fma contraction) so spike decisions are bit-stable vs the reference.

#define T_STEPS 512
#define D_DIM   1024

// f32(np.exp(-1/20)), f32(np.exp(-1/200))
#define ALPHA_MEM 0.9512294245007141f
#define ALPHA_ADP 0.9950124791926823f

__device__ __forceinline__ float adlif_step(float xv, float& v, float& a) {
    // v = alpha_mem * v + x_t
    v = __fadd_rn(__fmul_rn(ALPHA_MEM, v), xv);
    // cur_thr = THRESHOLD + BETA * a  (1.0 + 0.1*a)
    float cur = __fadd_rn(1.0f, __fmul_rn(0.1f, a));
    // s = (v - cur_thr >= THRESHOLD)   -- threshold counts twice, per ref
    float u = __fsub_rn(v, cur);
    float s = (u >= 1.0f) ? 1.0f : 0.0f;
    // a = alpha_adp * a + s
    a = __fadd_rn(__fmul_rn(ALPHA_ADP, a), s);
    // v = v - s * THRESHOLD  (THRESHOLD = 1, exact)
    v = __fsub_rn(v, s);
    return s;
}

__global__ __launch_bounds__(64) void adlif_kernel(const float* __restrict__ x,
                                                   float* __restrict__ out) {
    const int idx = blockIdx.x * 64 + threadIdx.x;   // 0 .. 32767
    const int b = idx >> 10;                          // / D_DIM
    const int d = idx & (D_DIM - 1);
    const size_t base = (size_t)b * (T_STEPS * D_DIM) + d;
    const float* xp = x + base;
    float* op = out + base;

    float v = 0.0f, a = 0.0f;

    constexpr int U = 16;
    float buf0[U], buf1[U];

#pragma unroll
    for (int i = 0; i < U; ++i) buf0[i] = xp[i * D_DIM];

    for (int t0 = 0; t0 < T_STEPS; t0 += 2 * U) {
        // prefetch group B (t0+U .. t0+2U-1)
#pragma unroll
        for (int i = 0; i < U; ++i) buf1[i] = xp[(t0 + U + i) * D_DIM];

        // compute group A
#pragma unroll
        for (int i = 0; i < U; ++i) {
            float s = adlif_step(buf0[i], v, a);
            op[(t0 + i) * D_DIM] = s;
        }

        // prefetch group A for next iteration (t0+2U .. t0+3U-1)
        if (t0 + 2 * U < T_STEPS) {
#pragma unroll
            for (int i = 0; i < U; ++i) buf0[i] = xp[(t0 + 2 * U + i) * D_DIM];
        }

        // compute group B
#pragma unroll
        for (int i = 0; i < U; ++i) {
            float s = adlif_step(buf1[i], v, a);
            op[(t0 + U + i) * D_DIM] = s;
        }
    }
}

extern "C" void kernel_launch(void* const* d_in, const int* in_sizes, int n_in,
                              void* d_out, int out_size, void* d_ws, size_t ws_size,
                              hipStream_t stream) {
    const float* x = (const float*)d_in[0];
    float* out = (float*)d_out;

    const int total = in_sizes[0];            // B*T*D = 16777216
    const int channels = total / T_STEPS;     // B*D  = 32768
    const int blocks = channels / 64;         // 512 blocks of 1 wave each

    adlif_kernel<<<blocks, 64, 0, stream>>>(x, out);
}

// Round 2
// 29.985 us; speedup vs baseline: 1.0631x; 1.0631x over previous
//
#include <hip/hip_runtime.h>

// AdLIF neuron scan: x [B=32, T=512, D=1024] f32 -> spikes [B, T, D] f32.
// One thread per (b, d) channel; sequential over T with 2x32-deep register
// prefetch ping-pong (up to 32 loads in flight per wave, 512 waves total).
// Non-temporal stores keep the (re-read) input resident in L2/L3.
//
// FP order matches the JAX reference exactly (mul then add, round-to-nearest,
// NO fma contraction) so spike decisions are bit-stable vs the reference.

#define T_STEPS 512
#define D_DIM   1024

// f32(np.exp(-1/20)), f32(np.exp(-1/200))
#define ALPHA_MEM 0.9512294245007141f
#define ALPHA_ADP 0.9950124791926823f

__device__ __forceinline__ float adlif_step(float xv, float& v, float& a) {
    // v = alpha_mem * v + x_t
    v = __fadd_rn(__fmul_rn(ALPHA_MEM, v), xv);
    // cur_thr = THRESHOLD + BETA * a  (1.0 + 0.1*a)
    float cur = __fadd_rn(1.0f, __fmul_rn(0.1f, a));
    // s = (v - cur_thr >= THRESHOLD)   -- threshold counts twice, per ref
    float u = __fsub_rn(v, cur);
    float s = (u >= 1.0f) ? 1.0f : 0.0f;
    // a = alpha_adp * a + s
    a = __fadd_rn(__fmul_rn(ALPHA_ADP, a), s);
    // v = v - s * THRESHOLD  (THRESHOLD = 1, exact)
    v = __fsub_rn(v, s);
    return s;
}

__global__ __launch_bounds__(64) void adlif_kernel(const float* __restrict__ x,
                                                   float* __restrict__ out) {
    const int idx = blockIdx.x * 64 + threadIdx.x;   // 0 .. 32767
    const int b = idx >> 10;                          // / D_DIM
    const int d = idx & (D_DIM - 1);
    const size_t base = (size_t)b * (T_STEPS * D_DIM) + d;
    const float* xp = x + base;
    float* op = out + base;

    float v = 0.0f, a = 0.0f;

    constexpr int U = 32;                 // pipeline depth per buffer
    float buf0[U], buf1[U];

#pragma unroll
    for (int i = 0; i < U; ++i) buf0[i] = xp[i * D_DIM];

    for (int t0 = 0; t0 < T_STEPS; t0 += 2 * U) {
        // prefetch group B (t0+U .. t0+2U-1)
#pragma unroll
        for (int i = 0; i < U; ++i) buf1[i] = xp[(t0 + U + i) * D_DIM];

        // compute group A (overlaps group-B loads in flight)
#pragma unroll
        for (int i = 0; i < U; ++i) {
            float s = adlif_step(buf0[i], v, a);
            __builtin_nontemporal_store(s, &op[(t0 + i) * D_DIM]);
        }

        // prefetch group A for next iteration (t0+2U .. t0+3U-1)
        if (t0 + 2 * U < T_STEPS) {
#pragma unroll
            for (int i = 0; i < U; ++i) buf0[i] = xp[(t0 + 2 * U + i) * D_DIM];
        }

        // compute group B
#pragma unroll
        for (int i = 0; i < U; ++i) {
            float s = adlif_step(buf1[i], v, a);
            __builtin_nontemporal_store(s, &op[(t0 + U + i) * D_DIM]);
        }
    }
}

extern "C" void kernel_launch(void* const* d_in, const int* in_sizes, int n_in,
                              void* d_out, int out_size, void* d_ws, size_t ws_size,
                              hipStream_t stream) {
    const float* x = (const float*)d_in[0];
    float* out = (float*)d_out;

    const int total = in_sizes[0];            // B*T*D = 16777216
    const int channels = total / T_STEPS;     // B*D  = 32768
    const int blocks = channels / 64;         // 512 blocks of 1 wave each

    adlif_kernel<<<blocks, 64, 0, stream>>>(x, out);
}